// Round 9
// baseline (687.260 us; speedup 1.0000x reference)
//
#include <hip/hip_runtime.h>

// SAGE_38113539785173 — 3-layer GraphSAGE inference on MI355X (gfx950).
// Round 18 == Round 16 resubmitted verbatim (rounds 16/17 died in GPU
// acquisition; kernel never ran). Theory unchanged:
// Round 16: dynamic-ticket load balancing for k_sage.
//   Round-12/15 result (379.5us): node-per-group gather confirmed the
//   concurrency model (hbm 1.87->2.33 TB/s, k_sage 109->88us). New signal:
//   OccupancyPercent 31.9% vs 50% resident — static grid-stride gives 6250
//   wave-iters over 4096 waves -> second sweep runs at 53% concurrency
//   (util 76%), and gather rate follows concurrency (proven twice).
//   Fix: per-layer global ticket counter (zeroed in k_btot). Each wave
//   atomically pulls 16-node chunks; next-ticket atomic issued BEFORE the
//   gather body so its latency hides under ~1us of gather. 6250 atomics on
//   one line per layer — negligible.
//   Everything else identical to round-15: node-per-group gather, fused BN
//   (stats epilogue + BNIN prologue), MFMA dual matmul, no-global-atomic
//   CSR build, NBLK=512, SG=1024 / 4 blocks/CU.

constexpr float BN_EPS = 1e-5f;

typedef __attribute__((ext_vector_type(8))) short bf16x8;
typedef __attribute__((ext_vector_type(4))) float f32x4;

// ---- bf16 helpers -----------------------------------------------------------
__device__ __forceinline__ float bf2f(unsigned short u) {
  union { unsigned int i; float f; } c;
  c.i = (unsigned int)u << 16;
  return c.f;
}
__device__ __forceinline__ unsigned short f2bf(float v) {
  union { float f; unsigned int i; } c;
  c.f = v;
  unsigned int r = c.i + 0x7fffu + ((c.i >> 16) & 1u);  // round-nearest-even
  return (unsigned short)(r >> 16);
}

__device__ __forceinline__ void st_f(float* p, size_t i, float v) { p[i] = v; }
__device__ __forceinline__ void st_f(unsigned short* p, size_t i, float v) {
  p[i] = f2bf(v);
}

// row loaders: 16 lanes x (16B fp32 | 8B bf16) per 64-channel row
__device__ __forceinline__ float4 ld_row(const float* p, int row, int li) {
  return ((const float4*)p)[(size_t)row * 16 + li];
}
__device__ __forceinline__ float4 ld_row(const unsigned short* p, int row, int li) {
  ushort4 u = ((const ushort4*)p)[(size_t)row * 16 + li];
  float4 f;
  f.x = bf2f(u.x); f.y = bf2f(u.y); f.z = bf2f(u.z); f.w = bf2f(u.w);
  return f;
}

// ---- edge dtype probe: deterministic, identical result in every block ------
__device__ __forceinline__ int probe_is32(const int* w, int E) {
  const int twoE = 2 * E;
  int f = 0;
#pragma unroll
  for (int j = 0; j < 32; ++j) {
    long long idx = (long long)(2 * j + 1) * twoE / 64;
    int wi = (int)(idx | 1);
    if (wi < twoE && w[wi] != 0) f = 1;
  }
  return f;
}

__device__ __forceinline__ void load_edge(const void* ei, int e, int E, int is32,
                                          int& src, int& dst) {
  if (is32) {
    const int* p = (const int*)ei;
    src = p[e];
    dst = p[E + e];
  } else {
    const long long* p = (const long long*)ei;
    src = (int)p[e];
    dst = (int)p[(long long)E + e];
  }
}

// --------------------------------- CSR phase 1: per-block bucket histograms
// hist layout TRANSPOSED: hist[bucket * NBLK + block]
__global__ __launch_bounds__(256) void k_hist(const void* __restrict__ ei, int E,
                                              int N, int NB, int NBLK, int chunk,
                                              int* __restrict__ hist) {
  __shared__ int h[256];
  h[threadIdx.x] = 0;
  const int is32 = probe_is32((const int*)ei, E);
  __syncthreads();
  int lo = blockIdx.x * chunk;
  int hi = lo + chunk;
  if (hi > E) hi = E;
  for (int e = lo + threadIdx.x; e < hi; e += 256) {
    int src, dst;
    load_edge(ei, e, E, is32, src, dst);
    if ((unsigned)src < (unsigned)N && (unsigned)dst < (unsigned)N)
      atomicAdd(&h[dst >> 9], 1);
  }
  __syncthreads();
  if (threadIdx.x < NB) hist[threadIdx.x * NBLK + blockIdx.x] = h[threadIdx.x];
}

// ---- CSR phase 2a: bucket totals + base offsets (+zero stats & tickets) ----
__global__ __launch_bounds__(256) void k_btot(const int* __restrict__ hist,
                                              int NBLK, int NB,
                                              int* __restrict__ bucket_base,
                                              float* __restrict__ stats,
                                              int* __restrict__ tickets) {
  stats[threadIdx.x] = 0.0f;  // zero both layers' raw-sum slots (256 floats)
  if (threadIdx.x < 8) tickets[threadIdx.x] = 0;  // per-layer ticket counters
  __shared__ int part[256];
  int t = threadIdx.x;
  int s = 0;
  if (t < NB) {
    const int4* hp = (const int4*)(hist + (size_t)t * NBLK);
    for (int b = 0; b < (NBLK >> 2); ++b) {
      int4 v = hp[b];
      s += v.x + v.y + v.z + v.w;
    }
  }
  part[t] = s;
  __syncthreads();
  for (int off = 1; off < 256; off <<= 1) {
    int u = (t >= off) ? part[t - off] : 0;
    __syncthreads();
    part[t] += u;
    __syncthreads();
  }
  if (t < NB) bucket_base[t] = part[t] - s;
  if (t == NB - 1) bucket_base[NB] = part[t];
}

// --------------------------------- CSR phase 2b: per-(block,bucket) offsets
__global__ __launch_bounds__(64) void k_hoff(const int* __restrict__ hist,
                                             int NBLK, int NB,
                                             const int* __restrict__ bucket_base,
                                             int* __restrict__ offs) {
  int b = blockIdx.x;
  int lane = threadIdx.x;
  int carry = bucket_base[b];
  for (int c = 0; c < NBLK; c += 64) {
    int blk = c + lane;
    int v = (blk < NBLK) ? hist[(size_t)b * NBLK + blk] : 0;  // coalesced
    int incl = v;
    for (int off = 1; off < 64; off <<= 1) {
      int u = __shfl_up(incl, off);
      if (lane >= off) incl += u;
    }
    if (blk < NBLK) offs[blk * NB + b] = carry + incl - v;
    carry += __shfl(incl, 63);
  }
}

// --------------------------------- CSR phase 3: bucket-grouped scatter
__global__ __launch_bounds__(256) void k_scat(const void* __restrict__ ei, int E,
                                              int N, int NB, int chunk,
                                              const int* __restrict__ offs,
                                              unsigned* __restrict__ csr) {
  __shared__ int cur[256];
  if (threadIdx.x < NB) cur[threadIdx.x] = offs[blockIdx.x * NB + threadIdx.x];
  const int is32 = probe_is32((const int*)ei, E);
  __syncthreads();
  int lo = blockIdx.x * chunk;
  int hi = lo + chunk;
  if (hi > E) hi = E;
  for (int e = lo + threadIdx.x; e < hi; e += 256) {
    int src, dst;
    load_edge(ei, e, E, is32, src, dst);
    if ((unsigned)src < (unsigned)N && (unsigned)dst < (unsigned)N) {
      int p = atomicAdd(&cur[dst >> 9], 1);
      csr[p] = ((unsigned)src << 9) | (unsigned)(dst & 511);
    }
  }
}

// --------------------------------- CSR phase 4: per-bucket fine permutation
__global__ __launch_bounds__(256) void k_fine(unsigned* __restrict__ csr,
                                              const int* __restrict__ bucket_base,
                                              int N, int* __restrict__ row_start) {
  constexpr int CAP = 12288;
  __shared__ unsigned lrec[CAP];
  __shared__ int lcnt[512];
  __shared__ int cur[512];
  __shared__ int wtot[4];
  const int b = blockIdx.x;
  const int lo = bucket_base[b];
  int cnt = bucket_base[b + 1] - lo;
  if (cnt > CAP) cnt = CAP;
  const int t = threadIdx.x;
  lcnt[t] = 0;
  lcnt[t + 256] = 0;
  __syncthreads();
  for (int i = t; i < cnt; i += 256) {
    unsigned r = csr[lo + i];
    lrec[i] = r;
    atomicAdd(&lcnt[r & 511], 1);
  }
  __syncthreads();
  int v0 = lcnt[2 * t], v1 = lcnt[2 * t + 1];
  int s = v0 + v1;
  int incl = s;
  const int lane = t & 63;
  for (int off = 1; off < 64; off <<= 1) {
    int u = __shfl_up(incl, off);
    if (lane >= off) incl += u;
  }
  const int wv = t >> 6;
  if (lane == 63) wtot[wv] = incl;
  __syncthreads();
  int woff = 0;
  for (int i = 0; i < wv; ++i) woff += wtot[i];
  int excl = woff + incl - s;
  cur[2 * t] = excl;
  cur[2 * t + 1] = excl + v0;
  int gi = b * 512 + 2 * t;
  if (gi <= N) row_start[gi] = lo + excl;
  if (gi + 1 <= N) row_start[gi + 1] = lo + excl + v0;
  __syncthreads();
  for (int i = t; i < cnt; i += 256) {
    unsigned r = lrec[i];
    int p = atomicAdd(&cur[r & 511], 1);
    csr[lo + p] = r >> 9;
  }
}

// --------------- fused gather-mean + MFMA dual matmul + BN-in + BN-out stats
// Gather: each 16-lane group owns one node (4 nodes/wave/pass, 4 passes).
// Work distribution: dynamic 16-node tickets via global atomic; next-ticket
// atomic issued before the body so latency hides under the gather.
template <int COUT, bool BNIN, bool BNOUT, typename TI, typename TO>
__global__ __launch_bounds__(256, 4) void k_sage(
    const TI* __restrict__ hin, const int* __restrict__ row_start,
    const int* __restrict__ csr, const float* __restrict__ Wl,
    const float* __restrict__ Wr, const float* __restrict__ bias,
    const float* __restrict__ statsIn, const float* __restrict__ gIn,
    const float* __restrict__ beIn, float* __restrict__ statsOut,
    int* __restrict__ ticket, TO* __restrict__ out, int n) {
  constexpr int NT = (COUT + 15) / 16;
  __shared__ short sWf[NT][4][64][8];  // B-fragments: [nt][kt][lane][j]
  __shared__ short sA[4][16][136];     // [wave][node][k: mean 0..63|self 64..127]
  __shared__ float sBN[2][64];         // BNIN: per-channel scale / shift
  __shared__ float sRed[2][4][64];     // BNOUT: per-wave channel partials

  for (int t = threadIdx.x; t < NT * 4 * 64; t += 256) {
    int lane = t & 63;
    int kt = (t >> 6) & 3;
    int nt = t >> 8;
    int kbase = kt * 32 + (lane >> 4) * 8;
    int col = nt * 16 + (lane & 15);
#pragma unroll
    for (int j = 0; j < 8; ++j) {
      int k = kbase + j;
      float wv = 0.0f;
      if (col < COUT) wv = (k < 64) ? Wl[k * COUT + col] : Wr[(k - 64) * COUT + col];
      sWf[nt][kt][lane][j] = (short)f2bf(wv);
    }
  }
  if (BNIN && threadIdx.x < 64) {
    int c = threadIdx.x;
    float inv = 1.0f / (float)n;
    float mu = statsIn[c] * inv;
    float var = statsIn[64 + c] * inv - mu * mu;
    var = var < 0.f ? 0.f : var;
    float sc = gIn[c] * rsqrtf(var + BN_EPS);
    sBN[0][c] = sc;
    sBN[1][c] = beIn[c] - mu * sc;
  }
  __syncthreads();

  const int wave = threadIdx.x >> 6;
  const int lane = threadIdx.x & 63;
  const int g = lane >> 4;
  const int li = lane & 15;
  const int quad = lane >> 4;
  const int col16 = lane & 15;

  // per-lane BN-in coefficients for channels li*4..li*4+3
  float4 bsc = make_float4(1.f, 1.f, 1.f, 1.f);
  float4 bsh = make_float4(0.f, 0.f, 0.f, 0.f);
  if (BNIN) {
    bsc = *(const float4*)&sBN[0][li * 4];
    bsh = *(const float4*)&sBN[1][li * 4];
  }
  auto xf = [&](float4 v) -> float4 {
    if (!BNIN) return v;
    float4 r;
    r.x = fmaxf(v.x * bsc.x + bsh.x, 0.f);
    r.y = fmaxf(v.y * bsc.y + bsh.y, 0.f);
    r.z = fmaxf(v.z * bsc.z + bsh.z, 0.f);
    r.w = fmaxf(v.w * bsc.w + bsh.w, 0.f);
    return r;
  };

  float bias_r[NT];
#pragma unroll
  for (int nt = 0; nt < NT; ++nt) {
    int c = nt * 16 + col16;
    bias_r[nt] = (c < COUT) ? bias[c] : 0.0f;
  }

  float statS[NT], statQ[NT];
#pragma unroll
  for (int nt = 0; nt < NT; ++nt) { statS[nt] = 0.f; statQ[nt] = 0.f; }

  // dynamic ticketing: wave pulls 16-node chunks; prefetch next ticket
  int tkt = 0;
  if (lane == 0) tkt = atomicAdd(ticket, 16);
  int base = __shfl(tkt, 0);

  while (base < n) {
    if (lane == 0) tkt = atomicAdd(ticket, 16);  // issued early, hides latency

    // gather: group g owns node base + pass*4 + g; lane-local channel sums
#pragma unroll 1
    for (int pass = 0; pass < 4; ++pass) {
      const int nb = pass * 4 + g;
      const int node = base + nb;
      const bool valid = node < n;
      int rs = valid ? row_start[node] : 0;
      int re = valid ? row_start[node + 1] : 0;
      float4 acc = make_float4(0.f, 0.f, 0.f, 0.f);
      int e = rs;
      for (; e + 3 < re; e += 4) {  // 4 rows in flight per group
        int r0 = csr[e], r1 = csr[e + 1], r2 = csr[e + 2], r3 = csr[e + 3];
        float4 a = xf(ld_row(hin, r0, li));
        float4 b = xf(ld_row(hin, r1, li));
        float4 c = xf(ld_row(hin, r2, li));
        float4 d = xf(ld_row(hin, r3, li));
        acc.x += (a.x + b.x) + (c.x + d.x);
        acc.y += (a.y + b.y) + (c.y + d.y);
        acc.z += (a.z + b.z) + (c.z + d.z);
        acc.w += (a.w + b.w) + (c.w + d.w);
      }
      for (; e + 1 < re; e += 2) {
        int r0 = csr[e], r1 = csr[e + 1];
        float4 a = xf(ld_row(hin, r0, li));
        float4 b = xf(ld_row(hin, r1, li));
        acc.x += a.x + b.x;
        acc.y += a.y + b.y;
        acc.z += a.z + b.z;
        acc.w += a.w + b.w;
      }
      for (; e < re; ++e) {
        float4 a = xf(ld_row(hin, csr[e], li));
        acc.x += a.x; acc.y += a.y; acc.z += a.z; acc.w += a.w;
      }
      if (valid) {
        int deg = re - rs;
        float invd = 1.0f / (float)(deg > 0 ? deg : 1);
        float4 self = xf(ld_row(hin, node, li));
        ushort4 mv, sv;
        mv.x = f2bf(acc.x * invd); mv.y = f2bf(acc.y * invd);
        mv.z = f2bf(acc.z * invd); mv.w = f2bf(acc.w * invd);
        sv.x = f2bf(self.x); sv.y = f2bf(self.y);
        sv.z = f2bf(self.z); sv.w = f2bf(self.w);
        *(ushort4*)&sA[wave][nb][li * 4] = mv;
        *(ushort4*)&sA[wave][nb][64 + li * 4] = sv;
      }
    }
    __builtin_amdgcn_wave_barrier();

    f32x4 acc[NT];
#pragma unroll
    for (int nt = 0; nt < NT; ++nt) acc[nt] = (f32x4){0.f, 0.f, 0.f, 0.f};
#pragma unroll
    for (int kt = 0; kt < 4; ++kt) {
      bf16x8 a = *(const bf16x8*)&sA[wave][lane & 15][kt * 32 + (lane >> 4) * 8];
#pragma unroll
      for (int nt = 0; nt < NT; ++nt) {
        bf16x8 b = *(const bf16x8*)&sWf[nt][kt][lane][0];
        acc[nt] = __builtin_amdgcn_mfma_f32_16x16x32_bf16(a, b, acc[nt], 0, 0, 0);
      }
    }
    __builtin_amdgcn_wave_barrier();

#pragma unroll
    for (int nt = 0; nt < NT; ++nt) {
      int c = nt * 16 + col16;
      if (c < COUT) {
#pragma unroll
        for (int r = 0; r < 4; ++r) {
          int node = base + quad * 4 + r;
          if (node < n) {
            float v = acc[nt][r] + bias_r[nt];
            st_f(out, (size_t)node * COUT + c, v);
            if (BNOUT) { statS[nt] += v; statQ[nt] += v * v; }
          }
        }
      }
    }

    base = __shfl(tkt, 0);  // consume prefetched ticket
  }

  if (BNOUT) {  // COUT==64 whenever BNOUT: every lane owns 4 real channels
#pragma unroll
    for (int nt = 0; nt < NT; ++nt) {
      statS[nt] += __shfl_xor(statS[nt], 16);
      statS[nt] += __shfl_xor(statS[nt], 32);
      statQ[nt] += __shfl_xor(statQ[nt], 16);
      statQ[nt] += __shfl_xor(statQ[nt], 32);
    }
    if (quad == 0) {
#pragma unroll
      for (int nt = 0; nt < NT; ++nt) {
        sRed[0][wave][nt * 16 + col16] = statS[nt];
        sRed[1][wave][nt * 16 + col16] = statQ[nt];
      }
    }
    __syncthreads();
    if (threadIdx.x < 64) {
      int c = threadIdx.x;
      float s = sRed[0][0][c] + sRed[0][1][c] + sRed[0][2][c] + sRed[0][3][c];
      float q = sRed[1][0][c] + sRed[1][1][c] + sRed[1][2][c] + sRed[1][3][c];
      atomicAdd(&statsOut[c], s);
      atomicAdd(&statsOut[64 + c], q);
    }
  }
}

// ------------------------------------------------------------------ launcher
extern "C" void kernel_launch(void* const* d_in, const int* in_sizes, int n_in,
                              void* d_out, int out_size, void* d_ws, size_t ws_size,
                              hipStream_t stream) {
  const float* x = (const float*)d_in[0];
  const void* ei = d_in[1];
  const float* Wl0 = (const float*)d_in[2];
  const float* Wr0 = (const float*)d_in[3];
  const float* b0 = (const float*)d_in[4];
  const float* Wl1 = (const float*)d_in[5];
  const float* Wr1 = (const float*)d_in[6];
  const float* b1 = (const float*)d_in[7];
  const float* Wl2 = (const float*)d_in[8];
  const float* Wr2 = (const float*)d_in[9];
  const float* b2 = (const float*)d_in[10];
  const float* g0 = (const float*)d_in[11];
  const float* be0 = (const float*)d_in[12];
  const float* g1 = (const float*)d_in[13];
  const float* be1 = (const float*)d_in[14];

  const int N = in_sizes[0] / 64;
  const int E = in_sizes[1] / 2;
  const int NB = (N + 511) >> 9;
  const int NBLK = 512;  // 2 blocks/CU for the edge scans
  const int chunk = (E + NBLK - 1) / NBLK;

  // ---- d_ws carve: ~7.6 MB ----
  char* w = (char*)d_ws;
  auto carve = [&](size_t bytes) {
    void* p = (void*)w;
    w += (bytes + 255) & ~(size_t)255;
    return p;
  };
  float* stats = (float*)carve(1024);  // [L0: sum|sumsq][L1: sum|sumsq]
  int* tickets = (int*)carve(256);     // per-layer dynamic work counters
  int* row_start = (int*)carve((size_t)(N + 1) * 4);
  unsigned* csr = (unsigned*)carve((size_t)E * 4);
  int* hist = (int*)carve((size_t)NBLK * NB * 4);  // TRANSPOSED [bucket][block]
  int* offs = (int*)carve((size_t)NBLK * NB * 4);
  int* bucket_base = (int*)carve((size_t)(NB + 1) * 4);

  float* statsA = stats;
  float* statsB = stats + 128;

  // feature buffers outside d_ws (both bf16, pre-BN):
  unsigned short* B = (unsigned short*)d_out;  // 12.8MB <= 16MB out buffer
  unsigned short* A = (unsigned short*)const_cast<float*>(x);  // x dead after L0

  const int SG = 1024;  // 4 blocks/CU resident

  // ---- CSR build (no global atomics, no probe dispatch) ----
  k_hist<<<NBLK, 256, 0, stream>>>(ei, E, N, NB, NBLK, chunk, hist);
  k_btot<<<1, 256, 0, stream>>>(hist, NBLK, NB, bucket_base, stats, tickets);
  k_hoff<<<NB, 64, 0, stream>>>(hist, NBLK, NB, bucket_base, offs);
  k_scat<<<NBLK, 256, 0, stream>>>(ei, E, N, NB, chunk, offs, csr);
  k_fine<<<NB, 256, 0, stream>>>(csr, bucket_base, N, row_start);

  // ---- layer 0: x (fp32) -> B (bf16 pre-BN in d_out); stats -> statsA ----
  k_sage<64, false, true, float, unsigned short><<<SG, 256, 0, stream>>>(
      x, row_start, (const int*)csr, Wl0, Wr0, b0,
      statsA, g0, be0, statsA, tickets + 0, B, N);

  // ---- layer 1: BN0(B) -> A (bf16 pre-BN in x's buffer); stats -> statsB ----
  k_sage<64, true, true, unsigned short, unsigned short><<<SG, 256, 0, stream>>>(
      B, row_start, (const int*)csr, Wl1, Wr1, b1,
      statsA, g0, be0, statsB, tickets + 1, A, N);

  // ---- layer 2: BN1(A) -> d_out (fp32, overwrites B scratch) ----
  k_sage<40, true, false, unsigned short, float><<<SG, 256, 0, stream>>>(
      A, row_start, (const int*)csr, Wl2, Wr2, b2,
      statsB, g1, be1, statsB, tickets + 2, (float*)d_out, N);
}

// Round 11
// 374.068 us; speedup vs baseline: 1.8373x; 1.8373x over previous
//
#include <hip/hip_runtime.h>

// SAGE_38113539785173 — 3-layer GraphSAGE inference on MI355X (gfx950).
// Round 20 == Round 19 resubmitted verbatim (round-19 bench died in GPU
// acquisition; kernel never ran). Theory unchanged:
// Round 19: balanced static grid (792 blocks) — no tickets.
//   Round-16/18 ticket experiment FAILED (687us): occupancy rose 32->40.5%
//   as predicted but hbm collapsed 2.33->1.07 TB/s, VALUBusy 7% — 4096
//   waves' returning atomicAdd on ONE cacheline serialize at the coherence
//   point (~100us startup queue). Ladder fact: same-line returning atomics
//   cost queue_depth x serialize_time; fatal when all waves hit it at once.
//   Fix the imbalance arithmetically instead: SG=792 blocks (99/XCD, 3168
//   waves) -> 6250 wave-iters = 3082x2 + 86x1, makespan 2 sweeps at 98.6%
//   slot fill (vs 1024 blocks: sweep2 at 53% fill). k_sage body is
//   byte-identical to round-15 (379.5us); only gridDim changes.
//   Independent tail fix: k_hist atomically accumulates per-bucket totals
//   (196 separate lines, 512 adds each — no same-line burst) so k_btot
//   reads 784B instead of scanning 400KB. btot_accum zeroed via
//   stream-ordered hipMemsetAsync (capture-legal; harness reset uses it).
// Node-per-group gather, fused BN (stats epilogue + BNIN prologue), MFMA
// dual matmul, no-global-atomic CSR build, NBLK=512 unchanged.

constexpr float BN_EPS = 1e-5f;

typedef __attribute__((ext_vector_type(8))) short bf16x8;
typedef __attribute__((ext_vector_type(4))) float f32x4;

// ---- bf16 helpers -----------------------------------------------------------
__device__ __forceinline__ float bf2f(unsigned short u) {
  union { unsigned int i; float f; } c;
  c.i = (unsigned int)u << 16;
  return c.f;
}
__device__ __forceinline__ unsigned short f2bf(float v) {
  union { float f; unsigned int i; } c;
  c.f = v;
  unsigned int r = c.i + 0x7fffu + ((c.i >> 16) & 1u);  // round-nearest-even
  return (unsigned short)(r >> 16);
}

__device__ __forceinline__ void st_f(float* p, size_t i, float v) { p[i] = v; }
__device__ __forceinline__ void st_f(unsigned short* p, size_t i, float v) {
  p[i] = f2bf(v);
}

// row loaders: 16 lanes x (16B fp32 | 8B bf16) per 64-channel row
__device__ __forceinline__ float4 ld_row(const float* p, int row, int li) {
  return ((const float4*)p)[(size_t)row * 16 + li];
}
__device__ __forceinline__ float4 ld_row(const unsigned short* p, int row, int li) {
  ushort4 u = ((const ushort4*)p)[(size_t)row * 16 + li];
  float4 f;
  f.x = bf2f(u.x); f.y = bf2f(u.y); f.z = bf2f(u.z); f.w = bf2f(u.w);
  return f;
}

// ---- edge dtype probe: deterministic, identical result in every block ------
__device__ __forceinline__ int probe_is32(const int* w, int E) {
  const int twoE = 2 * E;
  int f = 0;
#pragma unroll
  for (int j = 0; j < 32; ++j) {
    long long idx = (long long)(2 * j + 1) * twoE / 64;
    int wi = (int)(idx | 1);
    if (wi < twoE && w[wi] != 0) f = 1;
  }
  return f;
}

__device__ __forceinline__ void load_edge(const void* ei, int e, int E, int is32,
                                          int& src, int& dst) {
  if (is32) {
    const int* p = (const int*)ei;
    src = p[e];
    dst = p[E + e];
  } else {
    const long long* p = (const long long*)ei;
    src = (int)p[e];
    dst = (int)p[(long long)E + e];
  }
}

// --------------------------------- CSR phase 1: per-block bucket histograms
// hist layout TRANSPOSED: hist[bucket * NBLK + block]; also accumulates
// global per-bucket totals (196 distinct cachelines — no same-line burst).
__global__ __launch_bounds__(256) void k_hist(const void* __restrict__ ei, int E,
                                              int N, int NB, int NBLK, int chunk,
                                              int* __restrict__ hist,
                                              int* __restrict__ btot_accum) {
  __shared__ int h[256];
  h[threadIdx.x] = 0;
  const int is32 = probe_is32((const int*)ei, E);
  __syncthreads();
  int lo = blockIdx.x * chunk;
  int hi = lo + chunk;
  if (hi > E) hi = E;
  for (int e = lo + threadIdx.x; e < hi; e += 256) {
    int src, dst;
    load_edge(ei, e, E, is32, src, dst);
    if ((unsigned)src < (unsigned)N && (unsigned)dst < (unsigned)N)
      atomicAdd(&h[dst >> 9], 1);
  }
  __syncthreads();
  if (threadIdx.x < NB) {
    hist[threadIdx.x * NBLK + blockIdx.x] = h[threadIdx.x];
    atomicAdd(&btot_accum[threadIdx.x], h[threadIdx.x]);
  }
}

// ------- CSR phase 2a: scan pre-accumulated bucket totals (+zero stats) -----
__global__ __launch_bounds__(256) void k_btot(const int* __restrict__ btot_accum,
                                              int NB,
                                              int* __restrict__ bucket_base,
                                              float* __restrict__ stats) {
  stats[threadIdx.x] = 0.0f;  // zero both layers' raw-sum slots (256 floats)
  __shared__ int part[256];
  int t = threadIdx.x;
  int s = (t < NB) ? btot_accum[t] : 0;
  part[t] = s;
  __syncthreads();
  for (int off = 1; off < 256; off <<= 1) {
    int u = (t >= off) ? part[t - off] : 0;
    __syncthreads();
    part[t] += u;
    __syncthreads();
  }
  if (t < NB) bucket_base[t] = part[t] - s;
  if (t == NB - 1) bucket_base[NB] = part[t];
}

// --------------------------------- CSR phase 2b: per-(block,bucket) offsets
__global__ __launch_bounds__(64) void k_hoff(const int* __restrict__ hist,
                                             int NBLK, int NB,
                                             const int* __restrict__ bucket_base,
                                             int* __restrict__ offs) {
  int b = blockIdx.x;
  int lane = threadIdx.x;
  int carry = bucket_base[b];
  for (int c = 0; c < NBLK; c += 64) {
    int blk = c + lane;
    int v = (blk < NBLK) ? hist[(size_t)b * NBLK + blk] : 0;  // coalesced
    int incl = v;
    for (int off = 1; off < 64; off <<= 1) {
      int u = __shfl_up(incl, off);
      if (lane >= off) incl += u;
    }
    if (blk < NBLK) offs[blk * NB + b] = carry + incl - v;
    carry += __shfl(incl, 63);
  }
}

// --------------------------------- CSR phase 3: bucket-grouped scatter
__global__ __launch_bounds__(256) void k_scat(const void* __restrict__ ei, int E,
                                              int N, int NB, int chunk,
                                              const int* __restrict__ offs,
                                              unsigned* __restrict__ csr) {
  __shared__ int cur[256];
  if (threadIdx.x < NB) cur[threadIdx.x] = offs[blockIdx.x * NB + threadIdx.x];
  const int is32 = probe_is32((const int*)ei, E);
  __syncthreads();
  int lo = blockIdx.x * chunk;
  int hi = lo + chunk;
  if (hi > E) hi = E;
  for (int e = lo + threadIdx.x; e < hi; e += 256) {
    int src, dst;
    load_edge(ei, e, E, is32, src, dst);
    if ((unsigned)src < (unsigned)N && (unsigned)dst < (unsigned)N) {
      int p = atomicAdd(&cur[dst >> 9], 1);
      csr[p] = ((unsigned)src << 9) | (unsigned)(dst & 511);
    }
  }
}

// --------------------------------- CSR phase 4: per-bucket fine permutation
__global__ __launch_bounds__(256) void k_fine(unsigned* __restrict__ csr,
                                              const int* __restrict__ bucket_base,
                                              int N, int* __restrict__ row_start) {
  constexpr int CAP = 12288;
  __shared__ unsigned lrec[CAP];
  __shared__ int lcnt[512];
  __shared__ int cur[512];
  __shared__ int wtot[4];
  const int b = blockIdx.x;
  const int lo = bucket_base[b];
  int cnt = bucket_base[b + 1] - lo;
  if (cnt > CAP) cnt = CAP;
  const int t = threadIdx.x;
  lcnt[t] = 0;
  lcnt[t + 256] = 0;
  __syncthreads();
  for (int i = t; i < cnt; i += 256) {
    unsigned r = csr[lo + i];
    lrec[i] = r;
    atomicAdd(&lcnt[r & 511], 1);
  }
  __syncthreads();
  int v0 = lcnt[2 * t], v1 = lcnt[2 * t + 1];
  int s = v0 + v1;
  int incl = s;
  const int lane = t & 63;
  for (int off = 1; off < 64; off <<= 1) {
    int u = __shfl_up(incl, off);
    if (lane >= off) incl += u;
  }
  const int wv = t >> 6;
  if (lane == 63) wtot[wv] = incl;
  __syncthreads();
  int woff = 0;
  for (int i = 0; i < wv; ++i) woff += wtot[i];
  int excl = woff + incl - s;
  cur[2 * t] = excl;
  cur[2 * t + 1] = excl + v0;
  int gi = b * 512 + 2 * t;
  if (gi <= N) row_start[gi] = lo + excl;
  if (gi + 1 <= N) row_start[gi + 1] = lo + excl + v0;
  __syncthreads();
  for (int i = t; i < cnt; i += 256) {
    unsigned r = lrec[i];
    int p = atomicAdd(&cur[r & 511], 1);
    csr[lo + p] = r >> 9;
  }
}

// --------------- fused gather-mean + MFMA dual matmul + BN-in + BN-out stats
// Gather: each 16-lane group owns one node (4 nodes/wave/pass, 4 passes).
// Static grid-stride; launcher picks gridDim so the partition is balanced
// (makespan 2 sweeps, ~99% slot fill at N=100000 / SG=792).
template <int COUT, bool BNIN, bool BNOUT, typename TI, typename TO>
__global__ __launch_bounds__(256, 4) void k_sage(
    const TI* __restrict__ hin, const int* __restrict__ row_start,
    const int* __restrict__ csr, const float* __restrict__ Wl,
    const float* __restrict__ Wr, const float* __restrict__ bias,
    const float* __restrict__ statsIn, const float* __restrict__ gIn,
    const float* __restrict__ beIn, float* __restrict__ statsOut,
    TO* __restrict__ out, int n) {
  constexpr int NT = (COUT + 15) / 16;
  __shared__ short sWf[NT][4][64][8];  // B-fragments: [nt][kt][lane][j]
  __shared__ short sA[4][16][136];     // [wave][node][k: mean 0..63|self 64..127]
  __shared__ float sBN[2][64];         // BNIN: per-channel scale / shift
  __shared__ float sRed[2][4][64];     // BNOUT: per-wave channel partials

  for (int t = threadIdx.x; t < NT * 4 * 64; t += 256) {
    int lane = t & 63;
    int kt = (t >> 6) & 3;
    int nt = t >> 8;
    int kbase = kt * 32 + (lane >> 4) * 8;
    int col = nt * 16 + (lane & 15);
#pragma unroll
    for (int j = 0; j < 8; ++j) {
      int k = kbase + j;
      float wv = 0.0f;
      if (col < COUT) wv = (k < 64) ? Wl[k * COUT + col] : Wr[(k - 64) * COUT + col];
      sWf[nt][kt][lane][j] = (short)f2bf(wv);
    }
  }
  if (BNIN && threadIdx.x < 64) {
    int c = threadIdx.x;
    float inv = 1.0f / (float)n;
    float mu = statsIn[c] * inv;
    float var = statsIn[64 + c] * inv - mu * mu;
    var = var < 0.f ? 0.f : var;
    float sc = gIn[c] * rsqrtf(var + BN_EPS);
    sBN[0][c] = sc;
    sBN[1][c] = beIn[c] - mu * sc;
  }
  __syncthreads();

  const int wave = threadIdx.x >> 6;
  const int lane = threadIdx.x & 63;
  const int g = lane >> 4;
  const int li = lane & 15;
  const int quad = lane >> 4;
  const int col16 = lane & 15;

  // per-lane BN-in coefficients for channels li*4..li*4+3
  float4 bsc = make_float4(1.f, 1.f, 1.f, 1.f);
  float4 bsh = make_float4(0.f, 0.f, 0.f, 0.f);
  if (BNIN) {
    bsc = *(const float4*)&sBN[0][li * 4];
    bsh = *(const float4*)&sBN[1][li * 4];
  }
  auto xf = [&](float4 v) -> float4 {
    if (!BNIN) return v;
    float4 r;
    r.x = fmaxf(v.x * bsc.x + bsh.x, 0.f);
    r.y = fmaxf(v.y * bsc.y + bsh.y, 0.f);
    r.z = fmaxf(v.z * bsc.z + bsh.z, 0.f);
    r.w = fmaxf(v.w * bsc.w + bsh.w, 0.f);
    return r;
  };

  float bias_r[NT];
#pragma unroll
  for (int nt = 0; nt < NT; ++nt) {
    int c = nt * 16 + col16;
    bias_r[nt] = (c < COUT) ? bias[c] : 0.0f;
  }

  float statS[NT], statQ[NT];
#pragma unroll
  for (int nt = 0; nt < NT; ++nt) { statS[nt] = 0.f; statQ[nt] = 0.f; }

  const int wgl = blockIdx.x * 4 + wave;
  const int nstride = gridDim.x * 64;

  for (int base = wgl * 16; base < n; base += nstride) {
    // gather: group g owns node base + pass*4 + g; lane-local channel sums
#pragma unroll 1
    for (int pass = 0; pass < 4; ++pass) {
      const int nb = pass * 4 + g;
      const int node = base + nb;
      const bool valid = node < n;
      int rs = valid ? row_start[node] : 0;
      int re = valid ? row_start[node + 1] : 0;
      float4 acc = make_float4(0.f, 0.f, 0.f, 0.f);
      int e = rs;
      for (; e + 3 < re; e += 4) {  // 4 rows in flight per group
        int r0 = csr[e], r1 = csr[e + 1], r2 = csr[e + 2], r3 = csr[e + 3];
        float4 a = xf(ld_row(hin, r0, li));
        float4 b = xf(ld_row(hin, r1, li));
        float4 c = xf(ld_row(hin, r2, li));
        float4 d = xf(ld_row(hin, r3, li));
        acc.x += (a.x + b.x) + (c.x + d.x);
        acc.y += (a.y + b.y) + (c.y + d.y);
        acc.z += (a.z + b.z) + (c.z + d.z);
        acc.w += (a.w + b.w) + (c.w + d.w);
      }
      for (; e + 1 < re; e += 2) {
        int r0 = csr[e], r1 = csr[e + 1];
        float4 a = xf(ld_row(hin, r0, li));
        float4 b = xf(ld_row(hin, r1, li));
        acc.x += a.x + b.x;
        acc.y += a.y + b.y;
        acc.z += a.z + b.z;
        acc.w += a.w + b.w;
      }
      for (; e < re; ++e) {
        float4 a = xf(ld_row(hin, csr[e], li));
        acc.x += a.x; acc.y += a.y; acc.z += a.z; acc.w += a.w;
      }
      if (valid) {
        int deg = re - rs;
        float invd = 1.0f / (float)(deg > 0 ? deg : 1);
        float4 self = xf(ld_row(hin, node, li));
        ushort4 mv, sv;
        mv.x = f2bf(acc.x * invd); mv.y = f2bf(acc.y * invd);
        mv.z = f2bf(acc.z * invd); mv.w = f2bf(acc.w * invd);
        sv.x = f2bf(self.x); sv.y = f2bf(self.y);
        sv.z = f2bf(self.z); sv.w = f2bf(self.w);
        *(ushort4*)&sA[wave][nb][li * 4] = mv;
        *(ushort4*)&sA[wave][nb][64 + li * 4] = sv;
      }
    }
    __builtin_amdgcn_wave_barrier();

    f32x4 acc[NT];
#pragma unroll
    for (int nt = 0; nt < NT; ++nt) acc[nt] = (f32x4){0.f, 0.f, 0.f, 0.f};
#pragma unroll
    for (int kt = 0; kt < 4; ++kt) {
      bf16x8 a = *(const bf16x8*)&sA[wave][lane & 15][kt * 32 + (lane >> 4) * 8];
#pragma unroll
      for (int nt = 0; nt < NT; ++nt) {
        bf16x8 b = *(const bf16x8*)&sWf[nt][kt][lane][0];
        acc[nt] = __builtin_amdgcn_mfma_f32_16x16x32_bf16(a, b, acc[nt], 0, 0, 0);
      }
    }
    __builtin_amdgcn_wave_barrier();

#pragma unroll
    for (int nt = 0; nt < NT; ++nt) {
      int c = nt * 16 + col16;
      if (c < COUT) {
#pragma unroll
        for (int r = 0; r < 4; ++r) {
          int node = base + quad * 4 + r;
          if (node < n) {
            float v = acc[nt][r] + bias_r[nt];
            st_f(out, (size_t)node * COUT + c, v);
            if (BNOUT) { statS[nt] += v; statQ[nt] += v * v; }
          }
        }
      }
    }
  }

  if (BNOUT) {  // COUT==64 whenever BNOUT: every lane owns 4 real channels
#pragma unroll
    for (int nt = 0; nt < NT; ++nt) {
      statS[nt] += __shfl_xor(statS[nt], 16);
      statS[nt] += __shfl_xor(statS[nt], 32);
      statQ[nt] += __shfl_xor(statQ[nt], 16);
      statQ[nt] += __shfl_xor(statQ[nt], 32);
    }
    if (quad == 0) {
#pragma unroll
      for (int nt = 0; nt < NT; ++nt) {
        sRed[0][wave][nt * 16 + col16] = statS[nt];
        sRed[1][wave][nt * 16 + col16] = statQ[nt];
      }
    }
    __syncthreads();
    if (threadIdx.x < 64) {
      int c = threadIdx.x;
      float s = sRed[0][0][c] + sRed[0][1][c] + sRed[0][2][c] + sRed[0][3][c];
      float q = sRed[1][0][c] + sRed[1][1][c] + sRed[1][2][c] + sRed[1][3][c];
      atomicAdd(&statsOut[c], s);
      atomicAdd(&statsOut[64 + c], q);
    }
  }
}

// ------------------------------------------------------------------ launcher
extern "C" void kernel_launch(void* const* d_in, const int* in_sizes, int n_in,
                              void* d_out, int out_size, void* d_ws, size_t ws_size,
                              hipStream_t stream) {
  const float* x = (const float*)d_in[0];
  const void* ei = d_in[1];
  const float* Wl0 = (const float*)d_in[2];
  const float* Wr0 = (const float*)d_in[3];
  const float* b0 = (const float*)d_in[4];
  const float* Wl1 = (const float*)d_in[5];
  const float* Wr1 = (const float*)d_in[6];
  const float* b1 = (const float*)d_in[7];
  const float* Wl2 = (const float*)d_in[8];
  const float* Wr2 = (const float*)d_in[9];
  const float* b2 = (const float*)d_in[10];
  const float* g0 = (const float*)d_in[11];
  const float* be0 = (const float*)d_in[12];
  const float* g1 = (const float*)d_in[13];
  const float* be1 = (const float*)d_in[14];

  const int N = in_sizes[0] / 64;
  const int E = in_sizes[1] / 2;
  const int NB = (N + 511) >> 9;
  const int NBLK = 512;  // 2 blocks/CU for the edge scans
  const int chunk = (E + NBLK - 1) / NBLK;

  // ---- d_ws carve: ~7.6 MB ----
  char* w = (char*)d_ws;
  auto carve = [&](size_t bytes) {
    void* p = (void*)w;
    w += (bytes + 255) & ~(size_t)255;
    return p;
  };
  float* stats = (float*)carve(1024);      // [L0: sum|sumsq][L1: sum|sumsq]
  int* btot_accum = (int*)carve(1024);     // per-bucket edge totals (k_hist)
  int* row_start = (int*)carve((size_t)(N + 1) * 4);
  unsigned* csr = (unsigned*)carve((size_t)E * 4);
  int* hist = (int*)carve((size_t)NBLK * NB * 4);  // TRANSPOSED [bucket][block]
  int* offs = (int*)carve((size_t)NBLK * NB * 4);
  int* bucket_base = (int*)carve((size_t)(NB + 1) * 4);

  float* statsA = stats;
  float* statsB = stats + 128;

  // feature buffers outside d_ws (both bf16, pre-BN):
  unsigned short* B = (unsigned short*)d_out;  // 12.8MB <= 16MB out buffer
  unsigned short* A = (unsigned short*)const_cast<float*>(x);  // x dead after L0

  // Balanced static grid: SG*4 waves, each <=ceil(N/16 / (SG*4)) sweeps.
  // N=100000 -> 6250 wave-iters; SG=792 (99/XCD) -> 3168 waves, makespan 2,
  // slot fill 98.6% (vs SG=1024: sweep2 at 53% fill, measured Occ 31.9%).
  const int SG = 792;

  // ---- CSR build (no same-line atomic bursts, no probe dispatch) ----
  hipMemsetAsync(btot_accum, 0, 1024, stream);  // stream-ordered, capture-legal
  k_hist<<<NBLK, 256, 0, stream>>>(ei, E, N, NB, NBLK, chunk, hist, btot_accum);
  k_btot<<<1, 256, 0, stream>>>(btot_accum, NB, bucket_base, stats);
  k_hoff<<<NB, 64, 0, stream>>>(hist, NBLK, NB, bucket_base, offs);
  k_scat<<<NBLK, 256, 0, stream>>>(ei, E, N, NB, chunk, offs, csr);
  k_fine<<<NB, 256, 0, stream>>>(csr, bucket_base, N, row_start);

  // ---- layer 0: x (fp32) -> B (bf16 pre-BN in d_out); stats -> statsA ----
  k_sage<64, false, true, float, unsigned short><<<SG, 256, 0, stream>>>(
      x, row_start, (const int*)csr, Wl0, Wr0, b0,
      statsA, g0, be0, statsA, B, N);

  // ---- layer 1: BN0(B) -> A (bf16 pre-BN in x's buffer); stats -> statsB ----
  k_sage<64, true, true, unsigned short, unsigned short><<<SG, 256, 0, stream>>>(
      B, row_start, (const int*)csr, Wl1, Wr1, b1,
      statsA, g0, be0, statsB, A, N);

  // ---- layer 2: BN1(A) -> d_out (fp32, overwrites B scratch) ----
  k_sage<40, true, false, unsigned short, float><<<SG, 256, 0, stream>>>(
      A, row_start, (const int*)csr, Wl2, Wr2, b2,
      statsB, g1, be1, statsB, (float*)d_out, N);
}

// Round 15
// 354.100 us; speedup vs baseline: 1.9409x; 1.0564x over previous
//
#include <hip/hip_runtime.h>

// SAGE_38113539785173 — 3-layer GraphSAGE inference on MI355X (gfx950).
// Round 24 == Round 21 resubmitted verbatim (rounds 21/22/23 died in infra:
// container-fail, then two acquisition timeouts — kernel never ran). Theory
// unchanged:
// Round 21: 8-row-deep gather pipeline.
//   Round-19/20 result (374.1us): balanced grid was NEUTRAL on k_sage (87.6us,
//   2.33 TB/s flat) — effective waves 3124 vs 3113: aggregate concurrency
//   unchanged by construction. Schedule axis exhausted (4 blocks/CU LDS cap).
//   Rate-vs-concurrency curve (0.38 TB/s @ ~2 rows/wave r10; 2.33 @ nominal
//   16 r15) + Little's law (2.33 TB/s / 256 CU / ~9 waves = ~4-6 rows
//   actually in flight) => limiter is the PER-WAVE ISSUE WINDOW: the 4-deep
//   loop drains to zero at the adds. Fix: 8-row unrolled main loop (8 csr +
//   8 row loads issued before any consume), then 4/2/1 drains. ~99% of
//   Poisson(16) nodes enter the 8-loop. +~40 live VGPRs, budget 128.
//   Everything else byte-identical to round-20 (374us): node-per-group
//   gather, SG=792 balanced grid, fused BN, MFMA dual matmul, CSR build
//   with btot accumulation in k_hist, NBLK=512.

constexpr float BN_EPS = 1e-5f;

typedef __attribute__((ext_vector_type(8))) short bf16x8;
typedef __attribute__((ext_vector_type(4))) float f32x4;

// ---- bf16 helpers -----------------------------------------------------------
__device__ __forceinline__ float bf2f(unsigned short u) {
  union { unsigned int i; float f; } c;
  c.i = (unsigned int)u << 16;
  return c.f;
}
__device__ __forceinline__ unsigned short f2bf(float v) {
  union { float f; unsigned int i; } c;
  c.f = v;
  unsigned int r = c.i + 0x7fffu + ((c.i >> 16) & 1u);  // round-nearest-even
  return (unsigned short)(r >> 16);
}

__device__ __forceinline__ void st_f(float* p, size_t i, float v) { p[i] = v; }
__device__ __forceinline__ void st_f(unsigned short* p, size_t i, float v) {
  p[i] = f2bf(v);
}

// row loaders: 16 lanes x (16B fp32 | 8B bf16) per 64-channel row
__device__ __forceinline__ float4 ld_row(const float* p, int row, int li) {
  return ((const float4*)p)[(size_t)row * 16 + li];
}
__device__ __forceinline__ float4 ld_row(const unsigned short* p, int row, int li) {
  ushort4 u = ((const ushort4*)p)[(size_t)row * 16 + li];
  float4 f;
  f.x = bf2f(u.x); f.y = bf2f(u.y); f.z = bf2f(u.z); f.w = bf2f(u.w);
  return f;
}

// ---- edge dtype probe: deterministic, identical result in every block ------
__device__ __forceinline__ int probe_is32(const int* w, int E) {
  const int twoE = 2 * E;
  int f = 0;
#pragma unroll
  for (int j = 0; j < 32; ++j) {
    long long idx = (long long)(2 * j + 1) * twoE / 64;
    int wi = (int)(idx | 1);
    if (wi < twoE && w[wi] != 0) f = 1;
  }
  return f;
}

__device__ __forceinline__ void load_edge(const void* ei, int e, int E, int is32,
                                          int& src, int& dst) {
  if (is32) {
    const int* p = (const int*)ei;
    src = p[e];
    dst = p[E + e];
  } else {
    const long long* p = (const long long*)ei;
    src = (int)p[e];
    dst = (int)p[(long long)E + e];
  }
}

// --------------------------------- CSR phase 1: per-block bucket histograms
// hist layout TRANSPOSED: hist[bucket * NBLK + block]; also accumulates
// global per-bucket totals (196 distinct cachelines — no same-line burst).
__global__ __launch_bounds__(256) void k_hist(const void* __restrict__ ei, int E,
                                              int N, int NB, int NBLK, int chunk,
                                              int* __restrict__ hist,
                                              int* __restrict__ btot_accum) {
  __shared__ int h[256];
  h[threadIdx.x] = 0;
  const int is32 = probe_is32((const int*)ei, E);
  __syncthreads();
  int lo = blockIdx.x * chunk;
  int hi = lo + chunk;
  if (hi > E) hi = E;
  for (int e = lo + threadIdx.x; e < hi; e += 256) {
    int src, dst;
    load_edge(ei, e, E, is32, src, dst);
    if ((unsigned)src < (unsigned)N && (unsigned)dst < (unsigned)N)
      atomicAdd(&h[dst >> 9], 1);
  }
  __syncthreads();
  if (threadIdx.x < NB) {
    hist[threadIdx.x * NBLK + blockIdx.x] = h[threadIdx.x];
    atomicAdd(&btot_accum[threadIdx.x], h[threadIdx.x]);
  }
}

// ------- CSR phase 2a: scan pre-accumulated bucket totals (+zero stats) -----
__global__ __launch_bounds__(256) void k_btot(const int* __restrict__ btot_accum,
                                              int NB,
                                              int* __restrict__ bucket_base,
                                              float* __restrict__ stats) {
  stats[threadIdx.x] = 0.0f;  // zero both layers' raw-sum slots (256 floats)
  __shared__ int part[256];
  int t = threadIdx.x;
  int s = (t < NB) ? btot_accum[t] : 0;
  part[t] = s;
  __syncthreads();
  for (int off = 1; off < 256; off <<= 1) {
    int u = (t >= off) ? part[t - off] : 0;
    __syncthreads();
    part[t] += u;
    __syncthreads();
  }
  if (t < NB) bucket_base[t] = part[t] - s;
  if (t == NB - 1) bucket_base[NB] = part[t];
}

// --------------------------------- CSR phase 2b: per-(block,bucket) offsets
__global__ __launch_bounds__(64) void k_hoff(const int* __restrict__ hist,
                                             int NBLK, int NB,
                                             const int* __restrict__ bucket_base,
                                             int* __restrict__ offs) {
  int b = blockIdx.x;
  int lane = threadIdx.x;
  int carry = bucket_base[b];
  for (int c = 0; c < NBLK; c += 64) {
    int blk = c + lane;
    int v = (blk < NBLK) ? hist[(size_t)b * NBLK + blk] : 0;  // coalesced
    int incl = v;
    for (int off = 1; off < 64; off <<= 1) {
      int u = __shfl_up(incl, off);
      if (lane >= off) incl += u;
    }
    if (blk < NBLK) offs[blk * NB + b] = carry + incl - v;
    carry += __shfl(incl, 63);
  }
}

// --------------------------------- CSR phase 3: bucket-grouped scatter
__global__ __launch_bounds__(256) void k_scat(const void* __restrict__ ei, int E,
                                              int N, int NB, int chunk,
                                              const int* __restrict__ offs,
                                              unsigned* __restrict__ csr) {
  __shared__ int cur[256];
  if (threadIdx.x < NB) cur[threadIdx.x] = offs[blockIdx.x * NB + threadIdx.x];
  const int is32 = probe_is32((const int*)ei, E);
  __syncthreads();
  int lo = blockIdx.x * chunk;
  int hi = lo + chunk;
  if (hi > E) hi = E;
  for (int e = lo + threadIdx.x; e < hi; e += 256) {
    int src, dst;
    load_edge(ei, e, E, is32, src, dst);
    if ((unsigned)src < (unsigned)N && (unsigned)dst < (unsigned)N) {
      int p = atomicAdd(&cur[dst >> 9], 1);
      csr[p] = ((unsigned)src << 9) | (unsigned)(dst & 511);
    }
  }
}

// --------------------------------- CSR phase 4: per-bucket fine permutation
__global__ __launch_bounds__(256) void k_fine(unsigned* __restrict__ csr,
                                              const int* __restrict__ bucket_base,
                                              int N, int* __restrict__ row_start) {
  constexpr int CAP = 12288;
  __shared__ unsigned lrec[CAP];
  __shared__ int lcnt[512];
  __shared__ int cur[512];
  __shared__ int wtot[4];
  const int b = blockIdx.x;
  const int lo = bucket_base[b];
  int cnt = bucket_base[b + 1] - lo;
  if (cnt > CAP) cnt = CAP;
  const int t = threadIdx.x;
  lcnt[t] = 0;
  lcnt[t + 256] = 0;
  __syncthreads();
  for (int i = t; i < cnt; i += 256) {
    unsigned r = csr[lo + i];
    lrec[i] = r;
    atomicAdd(&lcnt[r & 511], 1);
  }
  __syncthreads();
  int v0 = lcnt[2 * t], v1 = lcnt[2 * t + 1];
  int s = v0 + v1;
  int incl = s;
  const int lane = t & 63;
  for (int off = 1; off < 64; off <<= 1) {
    int u = __shfl_up(incl, off);
    if (lane >= off) incl += u;
  }
  const int wv = t >> 6;
  if (lane == 63) wtot[wv] = incl;
  __syncthreads();
  int woff = 0;
  for (int i = 0; i < wv; ++i) woff += wtot[i];
  int excl = woff + incl - s;
  cur[2 * t] = excl;
  cur[2 * t + 1] = excl + v0;
  int gi = b * 512 + 2 * t;
  if (gi <= N) row_start[gi] = lo + excl;
  if (gi + 1 <= N) row_start[gi + 1] = lo + excl + v0;
  __syncthreads();
  for (int i = t; i < cnt; i += 256) {
    unsigned r = lrec[i];
    int p = atomicAdd(&cur[r & 511], 1);
    csr[lo + p] = r >> 9;
  }
}

// --------------- fused gather-mean + MFMA dual matmul + BN-in + BN-out stats
// Gather: each 16-lane group owns one node (4 nodes/wave/pass, 4 passes).
// 8-row-deep main loop: 8 csr + 8 row loads issued before any consume, so
// the per-wave VMEM queue stays ~8 deep instead of draining at each quad.
template <int COUT, bool BNIN, bool BNOUT, typename TI, typename TO>
__global__ __launch_bounds__(256, 4) void k_sage(
    const TI* __restrict__ hin, const int* __restrict__ row_start,
    const int* __restrict__ csr, const float* __restrict__ Wl,
    const float* __restrict__ Wr, const float* __restrict__ bias,
    const float* __restrict__ statsIn, const float* __restrict__ gIn,
    const float* __restrict__ beIn, float* __restrict__ statsOut,
    TO* __restrict__ out, int n) {
  constexpr int NT = (COUT + 15) / 16;
  __shared__ short sWf[NT][4][64][8];  // B-fragments: [nt][kt][lane][j]
  __shared__ short sA[4][16][136];     // [wave][node][k: mean 0..63|self 64..127]
  __shared__ float sBN[2][64];         // BNIN: per-channel scale / shift
  __shared__ float sRed[2][4][64];     // BNOUT: per-wave channel partials

  for (int t = threadIdx.x; t < NT * 4 * 64; t += 256) {
    int lane = t & 63;
    int kt = (t >> 6) & 3;
    int nt = t >> 8;
    int kbase = kt * 32 + (lane >> 4) * 8;
    int col = nt * 16 + (lane & 15);
#pragma unroll
    for (int j = 0; j < 8; ++j) {
      int k = kbase + j;
      float wv = 0.0f;
      if (col < COUT) wv = (k < 64) ? Wl[k * COUT + col] : Wr[(k - 64) * COUT + col];
      sWf[nt][kt][lane][j] = (short)f2bf(wv);
    }
  }
  if (BNIN && threadIdx.x < 64) {
    int c = threadIdx.x;
    float inv = 1.0f / (float)n;
    float mu = statsIn[c] * inv;
    float var = statsIn[64 + c] * inv - mu * mu;
    var = var < 0.f ? 0.f : var;
    float sc = gIn[c] * rsqrtf(var + BN_EPS);
    sBN[0][c] = sc;
    sBN[1][c] = beIn[c] - mu * sc;
  }
  __syncthreads();

  const int wave = threadIdx.x >> 6;
  const int lane = threadIdx.x & 63;
  const int g = lane >> 4;
  const int li = lane & 15;
  const int quad = lane >> 4;
  const int col16 = lane & 15;

  // per-lane BN-in coefficients for channels li*4..li*4+3
  float4 bsc = make_float4(1.f, 1.f, 1.f, 1.f);
  float4 bsh = make_float4(0.f, 0.f, 0.f, 0.f);
  if (BNIN) {
    bsc = *(const float4*)&sBN[0][li * 4];
    bsh = *(const float4*)&sBN[1][li * 4];
  }
  auto xf = [&](float4 v) -> float4 {
    if (!BNIN) return v;
    float4 r;
    r.x = fmaxf(v.x * bsc.x + bsh.x, 0.f);
    r.y = fmaxf(v.y * bsc.y + bsh.y, 0.f);
    r.z = fmaxf(v.z * bsc.z + bsh.z, 0.f);
    r.w = fmaxf(v.w * bsc.w + bsh.w, 0.f);
    return r;
  };

  float bias_r[NT];
#pragma unroll
  for (int nt = 0; nt < NT; ++nt) {
    int c = nt * 16 + col16;
    bias_r[nt] = (c < COUT) ? bias[c] : 0.0f;
  }

  float statS[NT], statQ[NT];
#pragma unroll
  for (int nt = 0; nt < NT; ++nt) { statS[nt] = 0.f; statQ[nt] = 0.f; }

  const int wgl = blockIdx.x * 4 + wave;
  const int nstride = gridDim.x * 64;

  for (int base = wgl * 16; base < n; base += nstride) {
    // gather: group g owns node base + pass*4 + g; lane-local channel sums
#pragma unroll 1
    for (int pass = 0; pass < 4; ++pass) {
      const int nb = pass * 4 + g;
      const int node = base + nb;
      const bool valid = node < n;
      int rs = valid ? row_start[node] : 0;
      int re = valid ? row_start[node + 1] : 0;
      float4 acc = make_float4(0.f, 0.f, 0.f, 0.f);
      int e = rs;
      for (; e + 7 < re; e += 8) {  // 8 rows in flight per group
        int r0 = csr[e], r1 = csr[e + 1], r2 = csr[e + 2], r3 = csr[e + 3];
        int r4 = csr[e + 4], r5 = csr[e + 5], r6 = csr[e + 6], r7 = csr[e + 7];
        float4 a0 = xf(ld_row(hin, r0, li));
        float4 a1 = xf(ld_row(hin, r1, li));
        float4 a2 = xf(ld_row(hin, r2, li));
        float4 a3 = xf(ld_row(hin, r3, li));
        float4 a4 = xf(ld_row(hin, r4, li));
        float4 a5 = xf(ld_row(hin, r5, li));
        float4 a6 = xf(ld_row(hin, r6, li));
        float4 a7 = xf(ld_row(hin, r7, li));
        acc.x += ((a0.x + a1.x) + (a2.x + a3.x)) + ((a4.x + a5.x) + (a6.x + a7.x));
        acc.y += ((a0.y + a1.y) + (a2.y + a3.y)) + ((a4.y + a5.y) + (a6.y + a7.y));
        acc.z += ((a0.z + a1.z) + (a2.z + a3.z)) + ((a4.z + a5.z) + (a6.z + a7.z));
        acc.w += ((a0.w + a1.w) + (a2.w + a3.w)) + ((a4.w + a5.w) + (a6.w + a7.w));
      }
      for (; e + 3 < re; e += 4) {  // 4-row drain
        int r0 = csr[e], r1 = csr[e + 1], r2 = csr[e + 2], r3 = csr[e + 3];
        float4 a0 = xf(ld_row(hin, r0, li));
        float4 a1 = xf(ld_row(hin, r1, li));
        float4 a2 = xf(ld_row(hin, r2, li));
        float4 a3 = xf(ld_row(hin, r3, li));
        acc.x += (a0.x + a1.x) + (a2.x + a3.x);
        acc.y += (a0.y + a1.y) + (a2.y + a3.y);
        acc.z += (a0.z + a1.z) + (a2.z + a3.z);
        acc.w += (a0.w + a1.w) + (a2.w + a3.w);
      }
      for (; e + 1 < re; e += 2) {  // 2-row drain
        int r0 = csr[e], r1 = csr[e + 1];
        float4 a0 = xf(ld_row(hin, r0, li));
        float4 a1 = xf(ld_row(hin, r1, li));
        acc.x += a0.x + a1.x;
        acc.y += a0.y + a1.y;
        acc.z += a0.z + a1.z;
        acc.w += a0.w + a1.w;
      }
      for (; e < re; ++e) {
        float4 a0 = xf(ld_row(hin, csr[e], li));
        acc.x += a0.x; acc.y += a0.y; acc.z += a0.z; acc.w += a0.w;
      }
      if (valid) {
        int deg = re - rs;
        float invd = 1.0f / (float)(deg > 0 ? deg : 1);
        float4 self = xf(ld_row(hin, node, li));
        ushort4 mv, sv;
        mv.x = f2bf(acc.x * invd); mv.y = f2bf(acc.y * invd);
        mv.z = f2bf(acc.z * invd); mv.w = f2bf(acc.w * invd);
        sv.x = f2bf(self.x); sv.y = f2bf(self.y);
        sv.z = f2bf(self.z); sv.w = f2bf(self.w);
        *(ushort4*)&sA[wave][nb][li * 4] = mv;
        *(ushort4*)&sA[wave][nb][64 + li * 4] = sv;
      }
    }
    __builtin_amdgcn_wave_barrier();

    f32x4 acc[NT];
#pragma unroll
    for (int nt = 0; nt < NT; ++nt) acc[nt] = (f32x4){0.f, 0.f, 0.f, 0.f};
#pragma unroll
    for (int kt = 0; kt < 4; ++kt) {
      bf16x8 a = *(const bf16x8*)&sA[wave][lane & 15][kt * 32 + (lane >> 4) * 8];
#pragma unroll
      for (int nt = 0; nt < NT; ++nt) {
        bf16x8 b = *(const bf16x8*)&sWf[nt][kt][lane][0];
        acc[nt] = __builtin_amdgcn_mfma_f32_16x16x32_bf16(a, b, acc[nt], 0, 0, 0);
      }
    }
    __builtin_amdgcn_wave_barrier();

#pragma unroll
    for (int nt = 0; nt < NT; ++nt) {
      int c = nt * 16 + col16;
      if (c < COUT) {
#pragma unroll
        for (int r = 0; r < 4; ++r) {
          int node = base + quad * 4 + r;
          if (node < n) {
            float v = acc[nt][r] + bias_r[nt];
            st_f(out, (size_t)node * COUT + c, v);
            if (BNOUT) { statS[nt] += v; statQ[nt] += v * v; }
          }
        }
      }
    }
  }

  if (BNOUT) {  // COUT==64 whenever BNOUT: every lane owns 4 real channels
#pragma unroll
    for (int nt = 0; nt < NT; ++nt) {
      statS[nt] += __shfl_xor(statS[nt], 16);
      statS[nt] += __shfl_xor(statS[nt], 32);
      statQ[nt] += __shfl_xor(statQ[nt], 16);
      statQ[nt] += __shfl_xor(statQ[nt], 32);
    }
    if (quad == 0) {
#pragma unroll
      for (int nt = 0; nt < NT; ++nt) {
        sRed[0][wave][nt * 16 + col16] = statS[nt];
        sRed[1][wave][nt * 16 + col16] = statQ[nt];
      }
    }
    __syncthreads();
    if (threadIdx.x < 64) {
      int c = threadIdx.x;
      float s = sRed[0][0][c] + sRed[0][1][c] + sRed[0][2][c] + sRed[0][3][c];
      float q = sRed[1][0][c] + sRed[1][1][c] + sRed[1][2][c] + sRed[1][3][c];
      atomicAdd(&statsOut[c], s);
      atomicAdd(&statsOut[64 + c], q);
    }
  }
}

// ------------------------------------------------------------------ launcher
extern "C" void kernel_launch(void* const* d_in, const int* in_sizes, int n_in,
                              void* d_out, int out_size, void* d_ws, size_t ws_size,
                              hipStream_t stream) {
  const float* x = (const float*)d_in[0];
  const void* ei = d_in[1];
  const float* Wl0 = (const float*)d_in[2];
  const float* Wr0 = (const float*)d_in[3];
  const float* b0 = (const float*)d_in[4];
  const float* Wl1 = (const float*)d_in[5];
  const float* Wr1 = (const float*)d_in[6];
  const float* b1 = (const float*)d_in[7];
  const float* Wl2 = (const float*)d_in[8];
  const float* Wr2 = (const float*)d_in[9];
  const float* b2 = (const float*)d_in[10];
  const float* g0 = (const float*)d_in[11];
  const float* be0 = (const float*)d_in[12];
  const float* g1 = (const float*)d_in[13];
  const float* be1 = (const float*)d_in[14];

  const int N = in_sizes[0] / 64;
  const int E = in_sizes[1] / 2;
  const int NB = (N + 511) >> 9;
  const int NBLK = 512;  // 2 blocks/CU for the edge scans
  const int chunk = (E + NBLK - 1) / NBLK;

  // ---- d_ws carve: ~7.6 MB ----
  char* w = (char*)d_ws;
  auto carve = [&](size_t bytes) {
    void* p = (void*)w;
    w += (bytes + 255) & ~(size_t)255;
    return p;
  };
  float* stats = (float*)carve(1024);      // [L0: sum|sumsq][L1: sum|sumsq]
  int* btot_accum = (int*)carve(1024);     // per-bucket edge totals (k_hist)
  int* row_start = (int*)carve((size_t)(N + 1) * 4);
  unsigned* csr = (unsigned*)carve((size_t)E * 4);
  int* hist = (int*)carve((size_t)NBLK * NB * 4);  // TRANSPOSED [bucket][block]
  int* offs = (int*)carve((size_t)NBLK * NB * 4);
  int* bucket_base = (int*)carve((size_t)(NB + 1) * 4);

  float* statsA = stats;
  float* statsB = stats + 128;

  // feature buffers outside d_ws (both bf16, pre-BN):
  unsigned short* B = (unsigned short*)d_out;  // 12.8MB <= 16MB out buffer
  unsigned short* A = (unsigned short*)const_cast<float*>(x);  // x dead after L0

  // Balanced static grid: 3168 waves -> 6250 wave-iters = 3082x2 + 86x1,
  // makespan 2 sweeps at 98.6% slot fill.
  const int SG = 792;

  // ---- CSR build (no same-line atomic bursts, no probe dispatch) ----
  hipMemsetAsync(btot_accum, 0, 1024, stream);  // stream-ordered, capture-legal
  k_hist<<<NBLK, 256, 0, stream>>>(ei, E, N, NB, NBLK, chunk, hist, btot_accum);
  k_btot<<<1, 256, 0, stream>>>(btot_accum, NB, bucket_base, stats);
  k_hoff<<<NB, 64, 0, stream>>>(hist, NBLK, NB, bucket_base, offs);
  k_scat<<<NBLK, 256, 0, stream>>>(ei, E, N, NB, chunk, offs, csr);
  k_fine<<<NB, 256, 0, stream>>>(csr, bucket_base, N, row_start);

  // ---- layer 0: x (fp32) -> B (bf16 pre-BN in d_out); stats -> statsA ----
  k_sage<64, false, true, float, unsigned short><<<SG, 256, 0, stream>>>(
      x, row_start, (const int*)csr, Wl0, Wr0, b0,
      statsA, g0, be0, statsA, B, N);

  // ---- layer 1: BN0(B) -> A (bf16 pre-BN in x's buffer); stats -> statsB ----
  k_sage<64, true, true, unsigned short, unsigned short><<<SG, 256, 0, stream>>>(
      B, row_start, (const int*)csr, Wl1, Wr1, b1,
      statsA, g0, be0, statsB, A, N);

  // ---- layer 2: BN1(A) -> d_out (fp32, overwrites B scratch) ----
  k_sage<40, true, false, unsigned short, float><<<SG, 256, 0, stream>>>(
      A, row_start, (const int*)csr, Wl2, Wr2, b2,
      statsB, g1, be1, statsB, (float*)d_out, N);
}